// Round 10
// baseline (233.988 us; speedup 1.0000x reference)
//
#include <hip/hip_runtime.h>

// QTT 3D sampling, round 10: SINGLE dispatch, manual device-scope barrier.
//   Phase A (512 blocks):
//     all blocks   : P3[d0,d1,d2,d3] = C0·C1·C2·C3  (block=(d0,d2,d3), M=8 GEMM)
//     blocks 0-63  : also T[d5,d6,d7] = C5·(C6·C7)  (before their P3 unit)
//     blocks 64-71 : also d4-bucket counting sort (bucket = bx-64, after P3)
//   -- device barrier (counter in d_ws; CAS-from-0xAAAAAAAA init; fenced) --
//   Phase B (512 units): V4 = gather(P3, prefix4) x C4[d4] (d4-grouped GEMM),
//     fused epilogue out[i] = dot(V4row, T[suffix3])
// Co-residency: LDS 42.3 KB -> 3 blocks/CU capacity; 512 blocks = 2/CU. Safe.
// Core shapes: (r_l, 8, r_{l+1}), ranks 1,8,64,256,256,256,64,8,1.
// C_l[k][d][s] at C_l[k*8*r_out + d*r_out + s].

typedef unsigned int u32;

#define NBLK 512u
#define POISON 0xAAAAAAAAu

__device__ __forceinline__ void async_load16(const float* g, float* l) {
    __builtin_amdgcn_global_load_lds(
        (const __attribute__((address_space(1))) u32*)g,
        (__attribute__((address_space(3))) u32*)l, 16, 0, 0);
}
__device__ __forceinline__ void fma4(float4& c, float a, const float4& b) {
    c.x = fmaf(a, b.x, c.x); c.y = fmaf(a, b.y, c.y);
    c.z = fmaf(a, b.z, c.z); c.w = fmaf(a, b.w, c.w);
}
__device__ __forceinline__ int digit_of(int x, int y, int z, int sh) {
    return 4*((x>>sh)&1) + 2*((y>>sh)&1) + ((z>>sh)&1);
}

__global__ __launch_bounds__(256, 4) void fused_kernel(
    const float* __restrict__ C0, const float* __restrict__ C1,
    const float* __restrict__ C2, const float* __restrict__ C3,
    const float* __restrict__ C4, const float* __restrict__ C5,
    const float* __restrict__ C6, const float* __restrict__ C7,
    const int* __restrict__ coords, int n,
    int* __restrict__ perms, int* __restrict__ bases,
    float* __restrict__ P3, float* __restrict__ T,
    u32* __restrict__ bar, float* __restrict__ out)
{
    __shared__ __align__(16) union {
        struct { int cnt[8]; int mybase; int rank; } p;
        struct { float S6s[8][64]; } b;
        struct { float v64[8][64]; float As[8][260]; float Bs[2][16][256]; } g;
        struct { float Arm[8][260]; float Bs[2][16][256]; } s4;
    } u;
    __shared__ int rows[8], aidx[8], qs[8];

    const int t = threadIdx.x;
    const int ln = t & 63, wv = t >> 6;
    const int bx = blockIdx.x;

    // ================= Phase A =================
    if (bx < 64) {
        // ---- T table: block = (d5, d6), all 8 d7 ----
        const int d5 = bx >> 3, d6 = bx & 7;
#pragma unroll
        for (int j = 0; j < 2; ++j) {
            const int idx = t + 256*j, d7 = idx >> 6, s = idx & 63;
            float acc = 0.f;
#pragma unroll
            for (int jj = 0; jj < 8; ++jj)
                acc = fmaf(C6[s*64 + d6*8 + jj], C7[jj*8 + d7], acc);
            u.b.S6s[d7][s] = acc;
        }
        __syncthreads();
        float4 creg[16];
#pragma unroll
        for (int s4i = 0; s4i < 16; ++s4i)
            creg[s4i] = *(const float4*)(C5 + (size_t)t*512 + d5*64 + s4i*4);
#pragma unroll 1
        for (int d7 = 0; d7 < 8; ++d7) {
            float acc = 0.f;
#pragma unroll
            for (int s4i = 0; s4i < 16; ++s4i) {
                const float4 a = creg[s4i];
                const float4 b = *(const float4*)&u.b.S6s[d7][s4i*4];
                acc = fmaf(a.x, b.x, acc); acc = fmaf(a.y, b.y, acc);
                acc = fmaf(a.z, b.z, acc); acc = fmaf(a.w, b.w, acc);
            }
            T[(size_t)((d5*8 + d6)*8 + d7)*256 + t] = acc;
        }
        __syncthreads();               // protect union before P3 part
    }

    {
        // ---- P3 table: block = (d0, d2, d3); rows = 8 d1 values ----
        const int d3 = bx & 7, d2 = (bx >> 3) & 7, d0 = bx >> 6;
        const float* Cd = C3 + d3 * 256;       // (k,c) at Cd[k*2048 + c]

        for (int r = wv; r < 16; r += 4)       // async B chunk 0
            async_load16(Cd + (size_t)r*2048 + ln*4, &u.g.Bs[0][r][ln*4]);

        // v64[d1][c] = sum_r C0[d0,r] * C1[r, d1, c]
#pragma unroll
        for (int j = 0; j < 2; ++j) {
            const int idx = t + 256*j, d1 = idx >> 6, c = idx & 63;
            float acc = 0.f;
#pragma unroll
            for (int r = 0; r < 8; ++r)
                acc = fmaf(C0[d0*8 + r], C1[r*512 + d1*64 + c], acc);
            u.g.v64[d1][c] = acc;
        }
        __syncthreads();

        // As[d1][k] = sum_j v64[d1][j] * C2[j, d2, k]; wave wv owns d1=wv*2+{0,1}
        {
            float4 a0 = make_float4(0,0,0,0), a1 = make_float4(0,0,0,0);
#pragma unroll 8
            for (int j = 0; j < 64; ++j) {
                const float4 c2 = *(const float4*)(C2 + (size_t)j*2048 + d2*256 + ln*4);
                fma4(a0, u.g.v64[wv*2 + 0][j], c2);
                fma4(a1, u.g.v64[wv*2 + 1][j], c2);
            }
            *(float4*)&u.g.As[wv*2 + 0][ln*4] = a0;
            *(float4*)&u.g.As[wv*2 + 1][ln*4] = a1;
        }
        __syncthreads();                        // As + B chunk0 ready

        float4 acc0 = make_float4(0,0,0,0), acc1 = make_float4(0,0,0,0);
        for (int c = 0; c < 16; ++c) {
            if (c + 1 < 16) {
                const int nb = (c+1) & 1;
                for (int r = wv; r < 16; r += 4)
                    async_load16(Cd + (size_t)((c+1)*16 + r)*2048 + ln*4,
                                 &u.g.Bs[nb][r][ln*4]);
            }
            const int cb = c & 1, kb = c * 16;
#pragma unroll 1
            for (int k4 = 0; k4 < 16; k4 += 4) {
                const float4 a0 = *(const float4*)&u.g.As[wv*2 + 0][kb + k4];
                const float4 a1 = *(const float4*)&u.g.As[wv*2 + 1][kb + k4];
                const float4 b0v = *(const float4*)&u.g.Bs[cb][k4+0][ln*4];
                const float4 b1v = *(const float4*)&u.g.Bs[cb][k4+1][ln*4];
                const float4 b2v = *(const float4*)&u.g.Bs[cb][k4+2][ln*4];
                const float4 b3v = *(const float4*)&u.g.Bs[cb][k4+3][ln*4];
                fma4(acc0, a0.x, b0v); fma4(acc0, a0.y, b1v);
                fma4(acc0, a0.z, b2v); fma4(acc0, a0.w, b3v);
                fma4(acc1, a1.x, b0v); fma4(acc1, a1.y, b1v);
                fma4(acc1, a1.z, b2v); fma4(acc1, a1.w, b3v);
            }
            __syncthreads();
        }
        {
            const int a0i = d0*512 + (wv*2 + 0)*64 + d2*8 + d3;
            const int a1i = d0*512 + (wv*2 + 1)*64 + d2*8 + d3;
            *(float4*)(P3 + (size_t)a0i*256 + ln*4) = acc0;
            *(float4*)(P3 + (size_t)a1i*256 + ln*4) = acc1;
        }
    }

    if (bx >= 64 && bx < 72) {
        // ---- d4 counting sort, bucket d = bx-64; 8 blocks in parallel ----
        const int d = bx - 64;
        __syncthreads();               // P3 part fully done with union
        if (t < 8) u.p.cnt[t] = 0;
        if (t == 8) u.p.rank = 0;
        __syncthreads();
        for (int i = t; i < n; i += 256) {
            const int dg = digit_of(coords[3*i], coords[3*i+1], coords[3*i+2], 3);
            atomicAdd(&u.p.cnt[dg], 1);
        }
        __syncthreads();
        if (t == 0) {
            int run = 0;
            for (int dd = 0; dd < 8; ++dd) {
                if (dd == d) u.p.mybase = run;
                if (d == 0) bases[dd] = run;
                run += u.p.cnt[dd];
            }
            if (d == 0) bases[8] = run;
        }
        __syncthreads();
        const int mb = u.p.mybase;
        for (int i = t; i < n; i += 256) {
            const int dg = digit_of(coords[3*i], coords[3*i+1], coords[3*i+2], 3);
            if (dg == d) {
                const int pos = atomicAdd(&u.p.rank, 1);
                perms[mb + pos] = i;
            }
        }
    }

    // ================= device barrier =================
    __threadfence();                   // release: drain + write back L2
    __syncthreads();
    if (t == 0) {
        atomicCAS(bar, POISON, 0u);    // exactly one block resets the poison
        atomicAdd(bar, 1u);
        u32 spins = 0;
        while (__hip_atomic_load(bar, __ATOMIC_RELAXED, __HIP_MEMORY_SCOPE_AGENT)
               < NBLK) {
            __builtin_amdgcn_s_sleep(16);
            if (++spins > (1u << 26)) break;   // safety valve: no permanent hang
        }
    }
    __syncthreads();
    __threadfence();                   // acquire: invalidate stale L2/L1 lines

    // ================= Phase B: stage4 + fused final =================
    {
        const int d  = bx & 7;
        const int ty = bx >> 3;        // 0..63
        const int b0 = bases[d], b1 = bases[d + 1];
        const int nrows = b1 - b0;
        const float* Cd = C4 + d * 256;

        for (int tile = ty; tile * 8 < nrows; tile += 64) {
            const int row0 = b0 + tile * 8;

            for (int r = wv; r < 16; r += 4)
                async_load16(Cd + (size_t)r*2048 + ln*4, &u.s4.Bs[0][r][ln*4]);
            if (t < 8) {
                const int gr = row0 + t;
                const int rr = (gr < b1) ? perms[gr] : -1;
                rows[t] = rr;
                int a = 0, q = 0;
                if (rr >= 0) {
                    const int x = coords[3*rr], y = coords[3*rr+1], z = coords[3*rr+2];
                    a = digit_of(x,y,z,7)*512 + digit_of(x,y,z,6)*64
                      + digit_of(x,y,z,5)*8 + digit_of(x,y,z,4);
                    q = digit_of(x,y,z,2)*64 + digit_of(x,y,z,1)*8 + digit_of(x,y,z,0);
                }
                aidx[t] = a; qs[t] = q;
            }
            __syncthreads();

            // gather A (8 x 256) from P3 prefix rows: 512 f4, 2/thread
#pragma unroll
            for (int j = 0; j < 2; ++j) {
                const int idx = t + 256*j, s = idx >> 6, c4 = idx & 63;
                float4 v = make_float4(0,0,0,0);
                if (rows[s] >= 0)
                    v = *(const float4*)(P3 + (size_t)aidx[s]*256 + c4*4);
                *(float4*)&u.s4.Arm[s][c4*4] = v;
            }
            __syncthreads();

            float4 acc0 = make_float4(0,0,0,0), acc1 = make_float4(0,0,0,0);

            for (int c = 0; c < 16; ++c) {
                if (c + 1 < 16) {
                    const int nb = (c+1) & 1;
                    for (int r = wv; r < 16; r += 4)
                        async_load16(Cd + (size_t)((c+1)*16 + r)*2048 + ln*4,
                                     &u.s4.Bs[nb][r][ln*4]);
                }
                const int cb = c & 1, kb = c * 16;
#pragma unroll 1
                for (int k4 = 0; k4 < 16; k4 += 4) {
                    const float4 a0 = *(const float4*)&u.s4.Arm[wv*2 + 0][kb + k4];
                    const float4 a1 = *(const float4*)&u.s4.Arm[wv*2 + 1][kb + k4];
                    const float4 b0v = *(const float4*)&u.s4.Bs[cb][k4+0][ln*4];
                    const float4 b1v = *(const float4*)&u.s4.Bs[cb][k4+1][ln*4];
                    const float4 b2v = *(const float4*)&u.s4.Bs[cb][k4+2][ln*4];
                    const float4 b3v = *(const float4*)&u.s4.Bs[cb][k4+3][ln*4];
                    fma4(acc0, a0.x, b0v); fma4(acc0, a0.y, b1v);
                    fma4(acc0, a0.z, b2v); fma4(acc0, a0.w, b3v);
                    fma4(acc1, a1.x, b0v); fma4(acc1, a1.y, b1v);
                    fma4(acc1, a1.z, b2v); fma4(acc1, a1.w, b3v);
                }
                __syncthreads();
            }

            // fused final: out[rr] = dot(V4row, T[q])
#pragma unroll
            for (int i = 0; i < 2; ++i) {
                const int s = wv*2 + i;
                const int rr = rows[s];
                float p = 0.f;
                if (rr >= 0) {
                    const float4 a = (i == 0) ? acc0 : acc1;
                    const float4 tv = *(const float4*)(T + (size_t)qs[s]*256 + ln*4);
                    p = fmaf(a.x, tv.x, fmaf(a.y, tv.y, fmaf(a.z, tv.z, a.w * tv.w)));
                }
                p += __shfl_xor(p, 1);
                p += __shfl_xor(p, 2);
                p += __shfl_xor(p, 4);
                p += __shfl_xor(p, 8);
                p += __shfl_xor(p, 16);
                p += __shfl_xor(p, 32);
                if (ln == 0 && rr >= 0) out[rr] = p;
            }
            __syncthreads();
        }
    }
}

extern "C" void kernel_launch(void* const* d_in, const int* in_sizes, int n_in,
                              void* d_out, int out_size, void* d_ws, size_t ws_size,
                              hipStream_t stream) {
    const float* C0 = (const float*)d_in[0];
    const float* C1 = (const float*)d_in[1];
    const float* C2 = (const float*)d_in[2];
    const float* C3 = (const float*)d_in[3];
    const float* C4 = (const float*)d_in[4];
    const float* C5 = (const float*)d_in[5];
    const float* C6 = (const float*)d_in[6];
    const float* C7 = (const float*)d_in[7];
    const int* coords = (const int*)d_in[8];
    float* out = (float*)d_out;

    const int n = in_sizes[8] / 3;

    // workspace (~4.5 MB)
    float* P3   = (float*)d_ws;                       // 4096*256
    float* Tt   = P3 + 4096*256;                      // 512*256
    int*   perms = (int*)(Tt + 512*256);              // n
    int*   bases = perms + (size_t)n;                 // 9 (+pad)
    u32*   bar   = (u32*)(bases + 16);                // barrier counter

    fused_kernel<<<NBLK, 256, 0, stream>>>(
        C0, C1, C2, C3, C4, C5, C6, C7, coords, n,
        perms, bases, P3, Tt, bar, out);
}

// Round 13
// 126.453 us; speedup vs baseline: 1.8504x; 1.8504x over previous
//
#include <hip/hip_runtime.h>

// QTT 3D sampling, round 13 (= R11 source; R11/R12 benches were broker/infra
// failures — "MI355X container failed twice" before any test output; every
// construct here ran on-device in R9/R10).
//   K1 (584 blocks, independent parts):
//     blocks 0-7   : d4 counting sort, one bucket per block (R10-verified)
//     blocks 8-71  : T[d5,d6,d7] = C5·(C6·C7)          (512 x 256 table)
//     blocks 72-583: P3[d0,d1,d2,d3] = C0·C1·C2·C3     (4096 x 256 table)
//   K2 (512 blocks): V4 = gather(P3, prefix4) x C4[d4] (d4-grouped GEMM),
//                    fused epilogue out[i] = dot(V4row, T[suffix3])
// Single-dispatch variants rejected: coop launch fails in harness (R8);
// manual device barrier costs ~150 us in cross-XCD atomics/fences (R10).
// Core shapes: (r_l, 8, r_{l+1}), ranks 1,8,64,256,256,256,64,8,1.
// C_l[k][d][s] at C_l[k*8*r_out + d*r_out + s].

typedef unsigned int u32;

__device__ __forceinline__ void async_load16(const float* g, float* l) {
    __builtin_amdgcn_global_load_lds(
        (const __attribute__((address_space(1))) u32*)g,
        (__attribute__((address_space(3))) u32*)l, 16, 0, 0);
}
__device__ __forceinline__ void fma4(float4& c, float a, const float4& b) {
    c.x = fmaf(a, b.x, c.x); c.y = fmaf(a, b.y, c.y);
    c.z = fmaf(a, b.z, c.z); c.w = fmaf(a, b.w, c.w);
}
__device__ __forceinline__ int digit_of(int x, int y, int z, int sh) {
    return 4*((x>>sh)&1) + 2*((y>>sh)&1) + ((z>>sh)&1);
}

// ---------------- K1: parallel sort + T table + dense P3 table ---------------
__global__ __launch_bounds__(256, 4) void tables_kernel(
    const float* __restrict__ C0, const float* __restrict__ C1,
    const float* __restrict__ C2, const float* __restrict__ C3,
    const float* __restrict__ C5, const float* __restrict__ C6,
    const float* __restrict__ C7,
    const int* __restrict__ coords, int n,
    int* __restrict__ perms, int* __restrict__ bases,
    float* __restrict__ P3, float* __restrict__ T)
{
    __shared__ __align__(16) union {
        struct { int cnt[8]; int mybase; int rank; } p;
        struct { float S6s[8][64]; } b;
        struct { float v64[8][64]; float As[8][260]; float Bs[2][16][256]; } g;
    } u;
    const int t = threadIdx.x;
    const int ln = t & 63, wv = t >> 6;
    const int bx = blockIdx.x;

    if (bx < 8) {
        // ---- d4 counting sort, bucket d = bx; 8 blocks in parallel ----
        const int d = bx;
        if (t < 8) u.p.cnt[t] = 0;
        if (t == 8) u.p.rank = 0;
        __syncthreads();
        for (int i = t; i < n; i += 256) {
            const int dg = digit_of(coords[3*i], coords[3*i+1], coords[3*i+2], 3);
            atomicAdd(&u.p.cnt[dg], 1);
        }
        __syncthreads();
        if (t == 0) {
            int run = 0;
            for (int dd = 0; dd < 8; ++dd) {
                if (dd == d) u.p.mybase = run;
                if (d == 0) bases[dd] = run;
                run += u.p.cnt[dd];
            }
            if (d == 0) bases[8] = run;
        }
        __syncthreads();
        const int mb = u.p.mybase;
        for (int i = t; i < n; i += 256) {
            const int dg = digit_of(coords[3*i], coords[3*i+1], coords[3*i+2], 3);
            if (dg == d) {
                const int pos = atomicAdd(&u.p.rank, 1);
                perms[mb + pos] = i;
            }
        }
    } else if (bx < 72) {
        // ---- T table: block = (d5, d6), all 8 d7 ----
        const int bb = bx - 8;
        const int d5 = bb >> 3, d6 = bb & 7;
#pragma unroll
        for (int j = 0; j < 2; ++j) {
            const int idx = t + 256*j, d7 = idx >> 6, s = idx & 63;
            float acc = 0.f;
#pragma unroll
            for (int jj = 0; jj < 8; ++jj)
                acc = fmaf(C6[s*64 + d6*8 + jj], C7[jj*8 + d7], acc);
            u.b.S6s[d7][s] = acc;
        }
        __syncthreads();
        float4 creg[16];
#pragma unroll
        for (int s4i = 0; s4i < 16; ++s4i)
            creg[s4i] = *(const float4*)(C5 + (size_t)t*512 + d5*64 + s4i*4);
#pragma unroll 1
        for (int d7 = 0; d7 < 8; ++d7) {
            float acc = 0.f;
#pragma unroll
            for (int s4i = 0; s4i < 16; ++s4i) {
                const float4 a = creg[s4i];
                const float4 b = *(const float4*)&u.b.S6s[d7][s4i*4];
                acc = fmaf(a.x, b.x, acc); acc = fmaf(a.y, b.y, acc);
                acc = fmaf(a.z, b.z, acc); acc = fmaf(a.w, b.w, acc);
            }
            T[(size_t)((d5*8 + d6)*8 + d7)*256 + t] = acc;
        }
    } else {
        // ---- P3 table: block = (d0, d2, d3); rows = 8 d1 values ----
        const int bb = bx - 72;
        const int d3 = bb & 7, d2 = (bb >> 3) & 7, d0 = bb >> 6;
        const float* Cd = C3 + d3 * 256;       // (k,c) at Cd[k*2048 + c]

        for (int r = wv; r < 16; r += 4)       // async B chunk 0
            async_load16(Cd + (size_t)r*2048 + ln*4, &u.g.Bs[0][r][ln*4]);

        // v64[d1][c] = sum_r C0[d0,r] * C1[r, d1, c]
#pragma unroll
        for (int j = 0; j < 2; ++j) {
            const int idx = t + 256*j, d1 = idx >> 6, c = idx & 63;
            float acc = 0.f;
#pragma unroll
            for (int r = 0; r < 8; ++r)
                acc = fmaf(C0[d0*8 + r], C1[r*512 + d1*64 + c], acc);
            u.g.v64[d1][c] = acc;
        }
        __syncthreads();

        // As[d1][k] = sum_j v64[d1][j] * C2[j, d2, k]; wave wv owns d1=wv*2+{0,1}
        {
            float4 a0 = make_float4(0,0,0,0), a1 = make_float4(0,0,0,0);
#pragma unroll 8
            for (int j = 0; j < 64; ++j) {
                const float4 c2 = *(const float4*)(C2 + (size_t)j*2048 + d2*256 + ln*4);
                fma4(a0, u.g.v64[wv*2 + 0][j], c2);
                fma4(a1, u.g.v64[wv*2 + 1][j], c2);
            }
            *(float4*)&u.g.As[wv*2 + 0][ln*4] = a0;
            *(float4*)&u.g.As[wv*2 + 1][ln*4] = a1;
        }
        __syncthreads();                        // As + B chunk0 ready

        float4 acc0 = make_float4(0,0,0,0), acc1 = make_float4(0,0,0,0);
        for (int c = 0; c < 16; ++c) {
            if (c + 1 < 16) {
                const int nb = (c+1) & 1;
                for (int r = wv; r < 16; r += 4)
                    async_load16(Cd + (size_t)((c+1)*16 + r)*2048 + ln*4,
                                 &u.g.Bs[nb][r][ln*4]);
            }
            const int cb = c & 1, kb = c * 16;
#pragma unroll 1
            for (int k4 = 0; k4 < 16; k4 += 4) {
                const float4 a0 = *(const float4*)&u.g.As[wv*2 + 0][kb + k4];
                const float4 a1 = *(const float4*)&u.g.As[wv*2 + 1][kb + k4];
                const float4 b0v = *(const float4*)&u.g.Bs[cb][k4+0][ln*4];
                const float4 b1v = *(const float4*)&u.g.Bs[cb][k4+1][ln*4];
                const float4 b2v = *(const float4*)&u.g.Bs[cb][k4+2][ln*4];
                const float4 b3v = *(const float4*)&u.g.Bs[cb][k4+3][ln*4];
                fma4(acc0, a0.x, b0v); fma4(acc0, a0.y, b1v);
                fma4(acc0, a0.z, b2v); fma4(acc0, a0.w, b3v);
                fma4(acc1, a1.x, b0v); fma4(acc1, a1.y, b1v);
                fma4(acc1, a1.z, b2v); fma4(acc1, a1.w, b3v);
            }
            __syncthreads();
        }
        // P3 row index a = d0*512 + d1*64 + d2*8 + d3
        {
            const int a0i = d0*512 + (wv*2 + 0)*64 + d2*8 + d3;
            const int a1i = d0*512 + (wv*2 + 1)*64 + d2*8 + d3;
            *(float4*)(P3 + (size_t)a0i*256 + ln*4) = acc0;
            *(float4*)(P3 + (size_t)a1i*256 + ln*4) = acc1;
        }
    }
}

// ---------------- K2: stage4 (gather P3, x C4[d4]) + fused final -------------
__global__ __launch_bounds__(256, 4) void stage4_final_kernel(
    const float* __restrict__ P3, const float* __restrict__ C4,
    const float* __restrict__ T, const int* __restrict__ coords,
    const int* __restrict__ perm, const int* __restrict__ base,
    float* __restrict__ out)
{
    const int d = blockIdx.x;
    const int b0 = base[d], b1 = base[d + 1];
    const int nrows = b1 - b0;
    const int t = threadIdx.x, ln = t & 63, wv = t >> 6;

    __shared__ __align__(16) float Arm[8][260];
    __shared__ __align__(16) float Bs[2][16][256];
    __shared__ int rows[8], aidx[8], qs[8];

    const float* Cd = C4 + d * 256;

    for (int tile = blockIdx.y; tile * 8 < nrows; tile += (int)gridDim.y) {
        const int row0 = b0 + tile * 8;

        for (int r = wv; r < 16; r += 4)
            async_load16(Cd + (size_t)r*2048 + ln*4, &Bs[0][r][ln*4]);
        if (t < 8) {
            const int gr = row0 + t;
            const int rr = (gr < b1) ? perm[gr] : -1;
            rows[t] = rr;
            int a = 0, q = 0;
            if (rr >= 0) {
                const int x = coords[3*rr], y = coords[3*rr+1], z = coords[3*rr+2];
                a = digit_of(x,y,z,7)*512 + digit_of(x,y,z,6)*64
                  + digit_of(x,y,z,5)*8 + digit_of(x,y,z,4);
                q = digit_of(x,y,z,2)*64 + digit_of(x,y,z,1)*8 + digit_of(x,y,z,0);
            }
            aidx[t] = a; qs[t] = q;
        }
        __syncthreads();

        // gather A (8 x 256) from P3 prefix rows: 512 f4, 2/thread
#pragma unroll
        for (int j = 0; j < 2; ++j) {
            const int idx = t + 256*j, s = idx >> 6, c4 = idx & 63;
            float4 v = make_float4(0,0,0,0);
            if (rows[s] >= 0)
                v = *(const float4*)(P3 + (size_t)aidx[s]*256 + c4*4);
            *(float4*)&Arm[s][c4*4] = v;
        }
        __syncthreads();

        float4 acc0 = make_float4(0,0,0,0), acc1 = make_float4(0,0,0,0);

        for (int c = 0; c < 16; ++c) {
            if (c + 1 < 16) {
                const int nb = (c+1) & 1;
                for (int r = wv; r < 16; r += 4)
                    async_load16(Cd + (size_t)((c+1)*16 + r)*2048 + ln*4,
                                 &Bs[nb][r][ln*4]);
            }
            const int cb = c & 1, kb = c * 16;
#pragma unroll 1
            for (int k4 = 0; k4 < 16; k4 += 4) {
                const float4 a0 = *(const float4*)&Arm[wv*2 + 0][kb + k4];
                const float4 a1 = *(const float4*)&Arm[wv*2 + 1][kb + k4];
                const float4 b0v = *(const float4*)&Bs[cb][k4+0][ln*4];
                const float4 b1v = *(const float4*)&Bs[cb][k4+1][ln*4];
                const float4 b2v = *(const float4*)&Bs[cb][k4+2][ln*4];
                const float4 b3v = *(const float4*)&Bs[cb][k4+3][ln*4];
                fma4(acc0, a0.x, b0v); fma4(acc0, a0.y, b1v);
                fma4(acc0, a0.z, b2v); fma4(acc0, a0.w, b3v);
                fma4(acc1, a1.x, b0v); fma4(acc1, a1.y, b1v);
                fma4(acc1, a1.z, b2v); fma4(acc1, a1.w, b3v);
            }
            __syncthreads();
        }

        // fused final: out[rr] = dot(V4row, T[q]); wave wv owns rows wv*2+{0,1}
#pragma unroll
        for (int i = 0; i < 2; ++i) {
            const int s = wv*2 + i;
            const int rr = rows[s];
            float p = 0.f;
            if (rr >= 0) {
                const float4 a = (i == 0) ? acc0 : acc1;
                const float4 tv = *(const float4*)(T + (size_t)qs[s]*256 + ln*4);
                p = fmaf(a.x, tv.x, fmaf(a.y, tv.y, fmaf(a.z, tv.z, a.w * tv.w)));
            }
            p += __shfl_xor(p, 1);
            p += __shfl_xor(p, 2);
            p += __shfl_xor(p, 4);
            p += __shfl_xor(p, 8);
            p += __shfl_xor(p, 16);
            p += __shfl_xor(p, 32);
            if (ln == 0 && rr >= 0) out[rr] = p;
        }
        __syncthreads();
    }
}

extern "C" void kernel_launch(void* const* d_in, const int* in_sizes, int n_in,
                              void* d_out, int out_size, void* d_ws, size_t ws_size,
                              hipStream_t stream) {
    const float* C0 = (const float*)d_in[0];
    const float* C1 = (const float*)d_in[1];
    const float* C2 = (const float*)d_in[2];
    const float* C3 = (const float*)d_in[3];
    const float* C4 = (const float*)d_in[4];
    const float* C5 = (const float*)d_in[5];
    const float* C6 = (const float*)d_in[6];
    const float* C7 = (const float*)d_in[7];
    const int* coords = (const int*)d_in[8];
    float* out = (float*)d_out;

    const int n = in_sizes[8] / 3;

    // workspace (~4.5 MB)
    float* P3   = (float*)d_ws;                       // 4096*256
    float* Tt   = P3 + 4096*256;                      // 512*256
    int*   perms = (int*)(Tt + 512*256);              // n
    int*   bases = perms + (size_t)n;                 // 9

    tables_kernel<<<584, 256, 0, stream>>>(
        C0, C1, C2, C3, C5, C6, C7, coords, n, perms, bases, P3, Tt);
    stage4_final_kernel<<<dim3(8, 64), 256, 0, stream>>>(
        P3, C4, Tt, coords, perms, bases, out);
}